// Round 10
// baseline (218.578 us; speedup 1.0000x reference)
//
#include <hip/hip_runtime.h>
#include <cstdint>
#include <cstddef>

#define BDIM 256
constexpr int Bn = 16;
constexpr int Tn = 20;
constexpr int Cn = 80;
constexpr int An = 33600;                 // 160^2 + 80^2 + 40^2
constexpr int BA = Bn * An;
constexpr int NBLK_C = BA / BDIM;         // 2100 exact
constexpr int MCAP = 4096;                // matched-anchor list capacity (true max 3200)
constexpr int LCAP = 128;                 // per-(b,t) matched cap (true max 75 by center rule)
constexpr int BLK_PER_IMG = An * 8 / BDIM; // 1050 exact (phaseA blocks never straddle images)

__device__ __forceinline__ float bce(float z, float y) {
    return fmaxf(z, 0.0f) - z * y + log1pf(expf(-fabsf(z)));
}

// ---- fast HW transcendentals (~1 ulp) — used ONLY in the discrete selection path ----
constexpr float LOG2E = 1.4426950408889634f;
constexpr float LN2   = 0.6931471805599453f;
__device__ __forceinline__ float fexp2(float x){ float r; asm("v_exp_f32 %0, %1" : "=v"(r) : "v"(x)); return r; }
__device__ __forceinline__ float flog2(float x){ float r; asm("v_log_f32 %0, %1" : "=v"(r) : "v"(x)); return r; }
__device__ __forceinline__ float frcp (float x){ float r; asm("v_rcp_f32 %0, %1" : "=v"(r) : "v"(x)); return r; }
__device__ __forceinline__ float fsqrt(float x){ float r; asm("v_sqrt_f32 %0, %1" : "=v"(r) : "v"(x)); return r; }
__device__ __forceinline__ float fsigm(float z){ return frcp(1.0f + fexp2(-z * LOG2E)); }
__device__ __forceinline__ float flogn(float x){ return flog2(x) * LN2; }

// monotone float->uint mapping (ascending uint == ascending float, handles negatives)
__device__ __forceinline__ uint32_t fkey(float f) {
    uint32_t b = __float_as_uint(f);
    return (b & 0x80000000u) ? ~b : (b | 0x80000000u);
}
__device__ __forceinline__ uint32_t unfkey(uint32_t u) {
    return (u & 0x80000000u) ? (u & 0x7FFFFFFFu) : ~u;
}
__device__ __forceinline__ uint64_t wmin64(uint64_t x) {
#pragma unroll
    for (int off = 1; off < 64; off <<= 1) {
        uint64_t o = (uint64_t)__shfl_xor((unsigned long long)x, off);
        x = (o < x) ? o : x;
    }
    return x;
}
__device__ __forceinline__ uint64_t wmax64(uint64_t x) {
#pragma unroll
    for (int off = 1; off < 64; off <<= 1) {
        uint64_t o = (uint64_t)__shfl_xor((unsigned long long)x, off);
        x = (o > x) ? o : x;
    }
    return x;
}

// ---------------- Phase A: 8 threads/anchor, fast trans; zeros mm/mcnt/done; tgt in LDS ----------------
__global__ __launch_bounds__(BDIM) void phaseA(
    const float* __restrict__ preds, const float* __restrict__ grid,
    const float* __restrict__ strd, const float* __restrict__ tgt,
    float4* __restrict__ box4, float* __restrict__ sobjv, float* __restrict__ objzv,
    float* __restrict__ Sbuf, uint32_t* __restrict__ fgim,
    uint32_t* __restrict__ mm, int* __restrict__ mcnt, int* __restrict__ done)
{
    __shared__ float tT[Tn * 6];
    int tid = threadIdx.x;
    int b = blockIdx.x / BLK_PER_IMG;             // blocks never straddle images
    if (tid < Tn * 6) tT[tid] = tgt[b * Tn * 6 + tid];
    if (blockIdx.x == 0 && tid == 0) { *mcnt = 0; *done = 0; }
    __syncthreads();

    int idx = blockIdx.x * BDIM + tid;            // over BA*8 threads
    int g = idx >> 3, q = idx & 7;
    int a = g - b * An;
    const float* r = preds + (size_t)g * 85;

    float objz = r[4];
    float sobj = fsigm(objz);
    float S2 = 0.0f;                              // sum of log2(1-pr)
#pragma unroll
    for (int cc = 0; cc < 10; ++cc) {
        int c = q + 8 * cc;
        float z = r[5 + c];
        float pr = fsqrt(sobj * fsigm(z));
        pr = fminf(fmaxf(pr, 1e-7f), 1.0f - 1e-7f);
        S2 += flog2(1.0f - pr);
    }
    S2 += __shfl_xor(S2, 1);
    S2 += __shfl_xor(S2, 2);
    S2 += __shfl_xor(S2, 4);

    float gx = grid[a * 2], gy = grid[a * 2 + 1], sv = strd[a];
    float xc = (gx + 0.5f) * sv, yc = (gy + 0.5f) * sv;
    uint32_t im_p = 0, fg_p = 0;
#pragma unroll
    for (int k = 0; k < 3; ++k) {
        int t = q + 8 * k;
        if (t < Tn) {
            const float* trr = tT + t * 6;
            bool valid = ((int)trr[0] == b);
            float x1 = trr[2], y1 = trr[3], x2 = trr[4], y2 = trr[5];
            float dmin = fminf(fminf(xc - x1, yc - y1), fminf(x2 - xc, y2 - yc));
            bool inb = (dmin > 0.0f) && valid;
            float cxt = (x1 + x2) * 0.5f, cyt = (y1 + y2) * 0.5f;
            bool inc = (fmaxf(fabsf(xc - cxt), fabsf(yc - cyt)) < 2.5f * sv) && valid;
            if (inb || inc) fg_p = 1u;
            if (inb && inc) im_p |= (1u << t);
        }
    }
    im_p |= __shfl_xor(im_p, 1); im_p |= __shfl_xor(im_p, 2); im_p |= __shfl_xor(im_p, 4);
    fg_p |= __shfl_xor(fg_p, 1); fg_p |= __shfl_xor(fg_p, 2); fg_p |= __shfl_xor(fg_p, 4);

    if (q == 0) {
        box4[g] = make_float4(r[0], r[1], r[2], r[3]);
        sobjv[g] = sobj; objzv[g] = objz; Sbuf[g] = S2 * LN2;
        fgim[g] = im_p | (fg_p ? 0x80000000u : 0u);
        mm[g] = 0u;
    }
}

// ---------------- Phase B (merged Bs+Bc): per (b,t) scan -> LDS cands + iou top-10
//                  -> cost top-10 -> dyn_k -> mm bits + exactly-once compaction ----------------
__global__ __launch_bounds__(BDIM) void phaseB(
    const float* __restrict__ preds, const float* __restrict__ tgt,
    const float4* __restrict__ box4, const float* __restrict__ sobjv,
    const float* __restrict__ Sbuf, const uint32_t* __restrict__ fgim,
    uint32_t* __restrict__ mm, int* __restrict__ mcnt, int* __restrict__ mlist)
{
    int bt = blockIdx.x;
    int b = bt / Tn, t = bt % Tn;
    const float* tr = tgt + (size_t)bt * 6;
    if ((int)tr[0] != b) return;
    int ct = (int)tr[1];
    float tx1 = tr[2], ty1 = tr[3], tx2 = tr[4], ty2 = tr[5];
    float areaT = (tx2 - tx1) * (ty2 - ty1);
    int tid = threadIdx.x, lane = tid & 63, wid = tid >> 6;
    int baseg = b * An;
    uint32_t tmask = 1u << t;

    __shared__ int s_cnt;
    __shared__ int s_cand[LCAP];
    if (tid == 0) s_cnt = 0;
    __syncthreads();

    // --- single scan: compact matched to LDS, fg-guarded iou top-10 in registers ---
    float V[10];
#pragma unroll
    for (int j = 0; j < 10; ++j) V[j] = 0.0f;
    for (int a = tid; a < An; a += BDIM) {
        int g = baseg + a;
        uint32_t fi = fgim[g];
        if (fi & tmask) {
            int p = atomicAdd(&s_cnt, 1);
            if (p < LCAP) s_cand[p] = a;
        }
        if (fi & 0x80000000u) {
            float4 pb = box4[g];
            float areaP = (pb.z - pb.x) * (pb.w - pb.y);
            float w = fmaxf(fminf(tx2, pb.z) - fmaxf(tx1, pb.x), 0.0f);
            float h = fmaxf(fminf(ty2, pb.w) - fmaxf(ty1, pb.y), 0.0f);
            float inter = w * h;
            float iou = inter / (areaT + areaP - inter + 1e-8f);
            if (iou > V[9]) {
                V[9] = iou;
#pragma unroll
                for (int j = 9; j > 0; --j) {
                    float hi = fmaxf(V[j-1], V[j]), lo = fminf(V[j-1], V[j]);
                    V[j-1] = hi; V[j] = lo;
                }
            }
        }
    }
    __syncthreads();
    int M = s_cnt;

    // --- per-wave iou top-10 (descending) -> wTop ---
    __shared__ float wTop[4][10];
    {
        float out[10];
#pragma unroll
        for (int r = 0; r < 10; ++r) {
            uint64_t pk = ((uint64_t)fkey(V[0]) << 32) | (uint32_t)lane;
            pk = wmax64(pk);
            int wl = (int)(pk & 63u);
            out[r] = __shfl(V[0], wl);
            bool win = (lane == wl);
#pragma unroll
            for (int j = 0; j < 9; ++j) V[j] = win ? V[j+1] : V[j];
            V[9] = win ? -1.0f : V[9];
        }
        if (lane == 0) {
#pragma unroll
            for (int r = 0; r < 10; ++r) wTop[wid][r] = out[r];
        }
    }

    // --- cost top-10: fast path over LDS candidates (all matched => no penalties), slow = full scan ---
    uint64_t L[10];
#pragma unroll
    for (int j = 0; j < 10; ++j) L[j] = ~0ULL;
    bool slow = (M < 10) || (M > LCAP);
    if (!slow) {
        for (int i = tid; i < M; i += BDIM) {
            int a = s_cand[i];
            int g = baseg + a;
            float4 pb = box4[g];
            float areaP = (pb.z - pb.x) * (pb.w - pb.y);
            float w = fmaxf(fminf(tx2, pb.z) - fmaxf(tx1, pb.x), 0.0f);
            float h = fmaxf(fminf(ty2, pb.w) - fmaxf(ty1, pb.y), 0.0f);
            float inter = w * h;
            float iou = inter / (areaT + areaP - inter + 1e-8f);
            float z = preds[(size_t)g * 85 + 5 + ct];
            float pr = fsqrt(sobjv[g] * fsigm(z));
            pr = fminf(fmaxf(pr, 1e-7f), 1.0f - 1e-7f);
            float clsc = -(flogn(pr) + Sbuf[g] - flogn(1.0f - pr));
            float cost = clsc - 3.0f * flogn(iou + 1e-8f);
            uint64_t k = ((uint64_t)fkey(cost) << 32) | (uint32_t)a;
            uint64_t m9 = (k < L[9]) ? k : L[9];
            L[9] = m9;
#pragma unroll
            for (int j = 9; j > 0; --j) {
                uint64_t lo = (L[j-1] < L[j]) ? L[j-1] : L[j];
                uint64_t hi = (L[j-1] < L[j]) ? L[j] : L[j-1];
                L[j-1] = lo; L[j] = hi;
            }
        }
    } else {
        for (int a = tid; a < An; a += BDIM) {
            int g = baseg + a;
            uint32_t fi = fgim[g];
            float4 pb = box4[g];
            float areaP = (pb.z - pb.x) * (pb.w - pb.y);
            float w = fmaxf(fminf(tx2, pb.z) - fmaxf(tx1, pb.x), 0.0f);
            float h = fmaxf(fminf(ty2, pb.w) - fmaxf(ty1, pb.y), 0.0f);
            float inter = w * h;
            float iou = inter / (areaT + areaP - inter + 1e-8f);
            float z = preds[(size_t)g * 85 + 5 + ct];
            float pr = fsqrt(sobjv[g] * fsigm(z));
            pr = fminf(fmaxf(pr, 1e-7f), 1.0f - 1e-7f);
            float clsc = -(flogn(pr) + Sbuf[g] - flogn(1.0f - pr));
            float cost = clsc - 3.0f * flogn(iou + 1e-8f)
                       + (((fi >> t) & 1u) ? 0.0f : 100000.0f)
                       + ((fi & 0x80000000u) ? 0.0f : 1000000.0f);
            uint64_t k = ((uint64_t)fkey(cost) << 32) | (uint32_t)a;
            uint64_t m9 = (k < L[9]) ? k : L[9];
            L[9] = m9;
#pragma unroll
            for (int j = 9; j > 0; --j) {
                uint64_t lo = (L[j-1] < L[j]) ? L[j-1] : L[j];
                uint64_t hi = (L[j-1] < L[j]) ? L[j] : L[j-1];
                L[j-1] = lo; L[j] = hi;
            }
        }
    }

    __shared__ uint64_t wT[4][10];
    __shared__ int s_sel[10];
    __shared__ int s_dynk;
    {
        uint64_t wout[10];
#pragma unroll
        for (int r = 0; r < 10; ++r) {
            uint64_t m = wmin64(L[0]);
            wout[r] = m;
            bool win = (L[0] == m) && (m != ~0ULL);
#pragma unroll
            for (int j = 0; j < 9; ++j) L[j] = win ? L[j+1] : L[j];
            L[9] = win ? ~0ULL : L[9];
        }
        if (lane == 0) {
#pragma unroll
            for (int r = 0; r < 10; ++r) wT[wid][r] = wout[r];
        }
    }
    __syncthreads();
    if (wid == 0) {
        // merge 40 wave-top cost keys -> global top-10 (ascending cost, lex)
        uint64_t x = (lane < 40) ? wT[lane / 10][lane % 10] : ~0ULL;
#pragma unroll
        for (int r = 0; r < 10; ++r) {
            uint64_t m = wmin64(x);
            if (lane == 0) s_sel[r] = (int)(m & 0xFFFFFFFFu);
            if (x == m && m != ~0ULL) x = ~0ULL;
        }
        // merge 40 wave-top iou values -> dyn_k (descending accumulate, same order as before)
        float xv = (lane < 40) ? wTop[lane / 10][lane % 10] : -1.0f;
        float accum = 0.0f;
#pragma unroll
        for (int r = 0; r < 10; ++r) {
            uint64_t pk = ((uint64_t)fkey(xv) << 32) | (uint32_t)lane;
            pk = wmax64(pk);
            int slot = (int)(pk & 0xFFFFFFFFu);
            accum += __uint_as_float(unfkey((uint32_t)(pk >> 32)));
            if (lane == slot) xv = -1.0f;
        }
        if (lane == 0) {
            int dynk = (int)accum;            // trunc == astype(int32)
            s_dynk = min(max(dynk, 1), 10);
        }
    }
    __syncthreads();
    if (tid < s_dynk) {
        int a = s_sel[tid];
        int g = baseg + a;
        if (fgim[g] & 0x80000000u) {
            if (atomicOr((unsigned int*)&mm[g], 1u << t) == 0u) {
                int pos = atomicAdd(mcnt, 1);
                if (pos < MCAP) mlist[pos] = g;
            }
        }
    }
}

// ---------------- Phase D: heavy per-matched-anchor loss (compact, tgt in LDS) ----------------
__global__ __launch_bounds__(BDIM) void phaseD(
    const float* __restrict__ preds, const float* __restrict__ tgt,
    const float4* __restrict__ box4, const float* __restrict__ sobjv,
    const float* __restrict__ Sbuf, const uint32_t* __restrict__ fgim,
    const uint32_t* __restrict__ mm, const int* __restrict__ mcnt,
    const int* __restrict__ mlist,
    float* __restrict__ lboxA, float* __restrict__ lobjA)
{
    __shared__ float tT[Bn * Tn * 6];
    for (int i = threadIdx.x; i < Bn * Tn * 6; i += BDIM) tT[i] = tgt[i];
    __syncthreads();

    int n = min(*mcnt, MCAP);
    for (int i = blockIdx.x * BDIM + threadIdx.x; i < n; i += gridDim.x * BDIM) {
        int g = mlist[i];
        int b = g / An;
        float4 pb = box4[g];
        float px1 = pb.x, py1 = pb.y, px2 = pb.z, py2 = pb.w;
        uint32_t m = mm[g];
        int pc = __popc(m);

        int at; float pred_iou;
        if (pc == 1) {
            at = __ffs(m) - 1;
            const float* trr = tT + (b * Tn + at) * 6;
            float tx1 = trr[2], ty1 = trr[3], tx2 = trr[4], ty2 = trr[5];
            float areaT = (tx2 - tx1) * (ty2 - ty1);
            float areaP = (px2 - px1) * (py2 - py1);
            float w = fmaxf(fminf(tx2, px2) - fmaxf(tx1, px1), 0.0f);
            float h = fmaxf(fminf(ty2, py2) - fmaxf(ty1, py1), 0.0f);
            float inter = w * h;
            pred_iou = inter / (areaT + areaP - inter + 1e-8f);
        } else {
            float S = Sbuf[g];
            uint32_t fi = fgim[g];
            float sobj = sobjv[g];
            float areaP = (px2 - px1) * (py2 - py1);
            float best = INFINITY;
            at = -1; pred_iou = 0.0f;
            for (int t = 0; t < Tn; ++t) {
                const float* trr = tT + (b * Tn + t) * 6;
                bool valid = ((int)trr[0] == b);
                int ctt = (int)trr[1];
                float tx1 = trr[2], ty1 = trr[3], tx2 = trr[4], ty2 = trr[5];
                float areaT = (tx2 - tx1) * (ty2 - ty1);
                float w = fmaxf(fminf(tx2, px2) - fmaxf(tx1, px1), 0.0f);
                float h = fmaxf(fminf(ty2, py2) - fmaxf(ty1, py1), 0.0f);
                float inter = w * h;
                float iou = inter / (areaT + areaP - inter + 1e-8f);
                float z = preds[(size_t)g * 85 + 5 + ctt];
                float pr = fsqrt(sobj * fsigm(z));
                pr = fminf(fmaxf(pr, 1e-7f), 1.0f - 1e-7f);
                float clsc = valid ? -(flogn(pr) + S - flogn(1.0f - pr)) : -S;
                float cost = clsc - 3.0f * flogn(iou + 1e-8f)
                           + (((fi >> t) & 1u) ? 0.0f : 100000.0f)
                           + ((fi & 0x80000000u) ? 0.0f : 1000000.0f)
                           + (valid ? 0.0f : 1000000000.0f);
                if (cost < best) { best = cost; at = t; pred_iou = iou; }
            }
        }

        const float* trr = tT + (b * Tn + at) * 6;
        float bx1 = trr[2], by1 = trr[3], bx2 = trr[4], by2 = trr[5];
        float w = fmaxf(fminf(px2, bx2) - fmaxf(px1, bx1), 0.0f);
        float h = fmaxf(fminf(py2, by2) - fmaxf(py1, by1), 0.0f);
        float inter = w * h;
        float wa = px2 - px1, ha = py2 - py1, wb = bx2 - bx1, hb = by2 - by1;
        float uni = wa * ha + wb * hb - inter + 1e-7f;
        float iou = inter / uni;
        float cw = fmaxf(px2, bx2) - fminf(px1, bx1);
        float ch = fmaxf(py2, by2) - fminf(py1, by1);
        float c2 = cw * cw + ch * ch + 1e-7f;
        float dx = px1 + px2 - bx1 - bx2, dy = py1 + py2 - by1 - by2;
        float rho2 = (dx * dx + dy * dy) / 4.0f;
        float dat = atanf(wb / (hb + 1e-7f)) - atanf(wa / (ha + 1e-7f));
        float v = 0.4052847345693511f * dat * dat;     // 4/pi^2
        float alpha = v / (1.0f - iou + v + 1e-7f);
        float ciou = iou - rho2 / c2 - alpha * v;

        int cls = (int)trr[1];
        bool pos = (pred_iou > 0.0f);
        const float* zp = preds + (size_t)g * 85 + 5;
        float lo = 0.0f;
        for (int c0 = 0; c0 < Cn; c0 += 8) {
            float z[8];
#pragma unroll
            for (int j = 0; j < 8; ++j) z[j] = zp[c0 + j];
#pragma unroll
            for (int j = 0; j < 8; ++j) {
                float y = (pos && (c0 + j) == cls) ? 0.95f : 6.329113924050633e-4f;
                lo += bce(z[j], y);
            }
        }
        lboxA[g] = 1.0f - ciou;
        lobjA[g] = lo;
    }
}

// ---------------- Phase EF: streaming assembly + fused reduce + last-block final ----------------
__global__ __launch_bounds__(BDIM) void phaseEF(
    const float* __restrict__ objzv, const uint32_t* __restrict__ mm,
    const float* __restrict__ lboxA, const float* __restrict__ lobjA,
    float* __restrict__ pLbox, float* __restrict__ pLobj,
    float* __restrict__ pLcls, float* __restrict__ pNpos,
    int* __restrict__ done, float* __restrict__ out)
{
    int tid = threadIdx.x;
    int g = blockIdx.x * BDIM + tid;
    uint32_t m = mm[g];
    bool matched = (m != 0u);
    float lbox_i = matched ? lboxA[g] : 0.0f;   // predicated: only written slots read
    float lobj_i = matched ? lobjA[g] : 0.0f;
    float npos_i = matched ? 1.0f : 0.0f;
    float lcls_i = bce(objzv[g], matched ? 1.0f : 0.0f);

    __shared__ float red4[4][BDIM];
    red4[0][tid] = lbox_i; red4[1][tid] = lobj_i;
    red4[2][tid] = lcls_i; red4[3][tid] = npos_i;
    __syncthreads();
    for (int s = BDIM / 2; s > 0; s >>= 1) {
        if (tid < s) {
            red4[0][tid] += red4[0][tid + s];
            red4[1][tid] += red4[1][tid + s];
            red4[2][tid] += red4[2][tid + s];
            red4[3][tid] += red4[3][tid + s];
        }
        __syncthreads();
    }
    __shared__ int s_last;
    if (tid == 0) {
        pLbox[blockIdx.x] = red4[0][0];
        pLobj[blockIdx.x] = red4[1][0];
        pLcls[blockIdx.x] = red4[2][0];
        pNpos[blockIdx.x] = red4[3][0];
        __threadfence();                          // release partials (device scope)
        int old = atomicAdd(done, 1);
        s_last = (old == NBLK_C - 1) ? 1 : 0;
    }
    __syncthreads();
    if (!s_last) return;
    __threadfence();                              // acquire all partials

    // finalK body verbatim (same order -> bit-identical)
    float s0 = 0, s1 = 0, s2 = 0, s3 = 0;
    for (int i = tid; i < NBLK_C; i += BDIM) {
        s0 += pLbox[i]; s1 += pLobj[i]; s2 += pLcls[i]; s3 += pNpos[i];
    }
    red4[0][tid] = s0; red4[1][tid] = s1; red4[2][tid] = s2; red4[3][tid] = s3;
    __syncthreads();
    for (int s = BDIM / 2; s > 0; s >>= 1) {
        if (tid < s) {
            red4[0][tid] += red4[0][tid + s];
            red4[1][tid] += red4[1][tid + s];
            red4[2][tid] += red4[2][tid + s];
            red4[3][tid] += red4[3][tid + s];
        }
        __syncthreads();
    }
    if (tid == 0) {
        float npos = fmaxf(red4[3][0], 1.0f);
        float lbox = red4[0][0] / npos;
        float lobj = red4[1][0] / (npos * (float)Cn);
        float lcls = red4[2][0] / (float)(Bn * An);
        out[0] = lbox + lobj + lcls;
        out[1] = lbox;
        out[2] = lobj;
        out[3] = lcls;
    }
}

extern "C" void kernel_launch(void* const* d_in, const int* in_sizes, int n_in,
                              void* d_out, int out_size, void* d_ws, size_t ws_size,
                              hipStream_t stream)
{
    (void)in_sizes; (void)n_in; (void)out_size; (void)ws_size;
    const float* preds = (const float*)d_in[0];
    const float* grid  = (const float*)d_in[1];
    const float* strd  = (const float*)d_in[2];
    const float* tgt   = (const float*)d_in[3];

    char* ws = (char*)d_ws;
    float4*   box4  = (float4*)ws;   ws += (size_t)BA * 16;
    float*    sobjv = (float*)ws;    ws += (size_t)BA * 4;
    float*    objzv = (float*)ws;    ws += (size_t)BA * 4;
    float*    Sbuf  = (float*)ws;    ws += (size_t)BA * 4;
    uint32_t* fgim  = (uint32_t*)ws; ws += (size_t)BA * 4;
    uint32_t* mm    = (uint32_t*)ws; ws += (size_t)BA * 4;
    int*      mcnt  = (int*)ws;      ws += 16;
    int*      done  = (int*)ws;      ws += 16;
    int*   mlist   = (int*)ws;       ws += (size_t)MCAP * 4;
    float* lboxA   = (float*)ws;     ws += (size_t)BA * 4;
    float* lobjA   = (float*)ws;     ws += (size_t)BA * 4;
    float* pLbox = (float*)ws;       ws += (size_t)NBLK_C * 4;
    float* pLobj = (float*)ws;       ws += (size_t)NBLK_C * 4;
    float* pLcls = (float*)ws;       ws += (size_t)NBLK_C * 4;
    float* pNpos = (float*)ws;       ws += (size_t)NBLK_C * 4;

    phaseA<<<Bn * BLK_PER_IMG, BDIM, 0, stream>>>(preds, grid, strd, tgt,
                                                  box4, sobjv, objzv, Sbuf, fgim,
                                                  mm, mcnt, done);
    phaseB<<<Bn * Tn, BDIM, 0, stream>>>(preds, tgt, box4, sobjv, Sbuf, fgim,
                                         mm, mcnt, mlist);
    phaseD<<<32, BDIM, 0, stream>>>(preds, tgt, box4, sobjv, Sbuf, fgim, mm,
                                    mcnt, mlist, lboxA, lobjA);
    phaseEF<<<NBLK_C, BDIM, 0, stream>>>(objzv, mm, lboxA, lobjA,
                                         pLbox, pLobj, pLcls, pNpos,
                                         done, (float*)d_out);
}

// Round 12
// 175.589 us; speedup vs baseline: 1.2448x; 1.2448x over previous
//
#include <hip/hip_runtime.h>
#include <cstdint>
#include <cstddef>

#define BDIM 256
constexpr int Bn = 16;
constexpr int Tn = 20;
constexpr int Cn = 80;
constexpr int An = 33600;                 // 160^2 + 80^2 + 40^2
constexpr int BA = Bn * An;
constexpr int NBLK_C = BA / BDIM;         // 2100 exact
constexpr int SL = 8;                     // slices per (b,t) in phaseBs
constexpr int ANB = An / SL;              // 4200 exact
constexpr int CAP = 2048;                 // matched-candidate list capacity
constexpr int MCAP = 4096;                // matched-anchor list capacity (true max 3200)
constexpr int BLK_PER_IMG = An * 8 / BDIM; // 1050 exact (phaseA blocks never straddle images)

__device__ __forceinline__ float bce(float z, float y) {
    return fmaxf(z, 0.0f) - z * y + log1pf(expf(-fabsf(z)));
}

// ---- fast HW transcendentals (~1 ulp) — used ONLY in the discrete selection path ----
constexpr float LOG2E = 1.4426950408889634f;
constexpr float LN2   = 0.6931471805599453f;
__device__ __forceinline__ float fexp2(float x){ float r; asm("v_exp_f32 %0, %1" : "=v"(r) : "v"(x)); return r; }
__device__ __forceinline__ float flog2(float x){ float r; asm("v_log_f32 %0, %1" : "=v"(r) : "v"(x)); return r; }
__device__ __forceinline__ float frcp (float x){ float r; asm("v_rcp_f32 %0, %1" : "=v"(r) : "v"(x)); return r; }
__device__ __forceinline__ float fsqrt(float x){ float r; asm("v_sqrt_f32 %0, %1" : "=v"(r) : "v"(x)); return r; }
__device__ __forceinline__ float fsigm(float z){ return frcp(1.0f + fexp2(-z * LOG2E)); }
__device__ __forceinline__ float flogn(float x){ return flog2(x) * LN2; }

// monotone float->uint mapping (ascending uint == ascending float, handles negatives)
__device__ __forceinline__ uint32_t fkey(float f) {
    uint32_t b = __float_as_uint(f);
    return (b & 0x80000000u) ? ~b : (b | 0x80000000u);
}
__device__ __forceinline__ uint32_t unfkey(uint32_t u) {
    return (u & 0x80000000u) ? (u & 0x7FFFFFFFu) : ~u;
}
__device__ __forceinline__ uint64_t wmin64(uint64_t x) {
#pragma unroll
    for (int off = 1; off < 64; off <<= 1) {
        uint64_t o = (uint64_t)__shfl_xor((unsigned long long)x, off);
        x = (o < x) ? o : x;
    }
    return x;
}
__device__ __forceinline__ uint64_t wmax64(uint64_t x) {
#pragma unroll
    for (int off = 1; off < 64; off <<= 1) {
        uint64_t o = (uint64_t)__shfl_xor((unsigned long long)x, off);
        x = (o > x) ? o : x;
    }
    return x;
}

// ---------------- Phase A: 8 threads/anchor, fast trans; zeros mm/cnt/mcnt/done; tgt in LDS ----------------
__global__ __launch_bounds__(BDIM) void phaseA(
    const float* __restrict__ preds, const float* __restrict__ grid,
    const float* __restrict__ strd, const float* __restrict__ tgt,
    float4* __restrict__ box4, float* __restrict__ sobjv, float* __restrict__ objzv,
    float* __restrict__ Sbuf, uint32_t* __restrict__ fgim,
    uint32_t* __restrict__ mm, int* __restrict__ cnt, int* __restrict__ mcnt,
    int* __restrict__ done)
{
    __shared__ float tT[Tn * 6];
    int tid = threadIdx.x;
    int b = blockIdx.x / BLK_PER_IMG;             // blocks never straddle images
    if (tid < Tn * 6) tT[tid] = tgt[b * Tn * 6 + tid];
    if (blockIdx.x == 0) {                        // zero selection counters (runs pre-phaseBs)
        for (int i = tid; i < Bn * Tn; i += BDIM) cnt[i] = 0;
        if (tid == 0) { *mcnt = 0; *done = 0; }
    }
    __syncthreads();

    int idx = blockIdx.x * BDIM + tid;            // over BA*8 threads
    int g = idx >> 3, q = idx & 7;
    int a = g - b * An;
    const float* r = preds + (size_t)g * 85;

    float objz = r[4];
    float sobj = fsigm(objz);
    float S2 = 0.0f;                              // sum of log2(1-pr)
#pragma unroll
    for (int cc = 0; cc < 10; ++cc) {
        int c = q + 8 * cc;
        float z = r[5 + c];
        float pr = fsqrt(sobj * fsigm(z));
        pr = fminf(fmaxf(pr, 1e-7f), 1.0f - 1e-7f);
        S2 += flog2(1.0f - pr);
    }
    S2 += __shfl_xor(S2, 1);
    S2 += __shfl_xor(S2, 2);
    S2 += __shfl_xor(S2, 4);

    float gx = grid[a * 2], gy = grid[a * 2 + 1], sv = strd[a];
    float xc = (gx + 0.5f) * sv, yc = (gy + 0.5f) * sv;
    uint32_t im_p = 0, fg_p = 0;
#pragma unroll
    for (int k = 0; k < 3; ++k) {
        int t = q + 8 * k;
        if (t < Tn) {
            const float* trr = tT + t * 6;
            bool valid = ((int)trr[0] == b);
            float x1 = trr[2], y1 = trr[3], x2 = trr[4], y2 = trr[5];
            float dmin = fminf(fminf(xc - x1, yc - y1), fminf(x2 - xc, y2 - yc));
            bool inb = (dmin > 0.0f) && valid;
            float cxt = (x1 + x2) * 0.5f, cyt = (y1 + y2) * 0.5f;
            bool inc = (fmaxf(fabsf(xc - cxt), fabsf(yc - cyt)) < 2.5f * sv) && valid;
            if (inb || inc) fg_p = 1u;
            if (inb && inc) im_p |= (1u << t);
        }
    }
    im_p |= __shfl_xor(im_p, 1); im_p |= __shfl_xor(im_p, 2); im_p |= __shfl_xor(im_p, 4);
    fg_p |= __shfl_xor(fg_p, 1); fg_p |= __shfl_xor(fg_p, 2); fg_p |= __shfl_xor(fg_p, 4);

    if (q == 0) {
        box4[g] = make_float4(r[0], r[1], r[2], r[3]);
        sobjv[g] = sobj; objzv[g] = objz; Sbuf[g] = S2 * LN2;
        fgim[g] = im_p | (fg_p ? 0x80000000u : 0u);
        mm[g] = 0u;
    }
}

// ---------------- Phase Bs: slice-parallel cheap scan (2560 blocks) ----------------
__global__ __launch_bounds__(BDIM) void phaseBs(
    const float* __restrict__ tgt, const float4* __restrict__ box4,
    const uint32_t* __restrict__ fgim,
    int* __restrict__ cnt, int* __restrict__ candIdx, float* __restrict__ candV)
{
    int bt = blockIdx.x / SL, sl = blockIdx.x % SL;
    int b = bt / Tn, t = bt % Tn;
    const float* tr = tgt + (size_t)bt * 6;
    if ((int)tr[0] != b) return;
    float tx1 = tr[2], ty1 = tr[3], tx2 = tr[4], ty2 = tr[5];
    float areaT = (tx2 - tx1) * (ty2 - ty1);
    int tid = threadIdx.x;
    int baseg = b * An;
    uint32_t tmask = 1u << t;

    float V[10];                          // sorted desc, branch-free inserts
#pragma unroll
    for (int j = 0; j < 10; ++j) V[j] = 0.0f;

    int aend = (sl + 1) * ANB;
    for (int a = sl * ANB + tid; a < aend; a += BDIM) {
        int g = baseg + a;
        uint32_t fi = fgim[g];
        if (fi & tmask) {
            int pos = atomicAdd(&cnt[bt], 1);
            if (pos < CAP) candIdx[bt * CAP + pos] = a;
        }
        if (fi & 0x80000000u) {
            float4 pb = box4[g];
            float areaP = (pb.z - pb.x) * (pb.w - pb.y);
            float w = fmaxf(fminf(tx2, pb.z) - fmaxf(tx1, pb.x), 0.0f);
            float h = fmaxf(fminf(ty2, pb.w) - fmaxf(ty1, pb.y), 0.0f);
            float inter = w * h;
            float iou = inter / (areaT + areaP - inter + 1e-8f);
            if (iou > V[9]) {
                V[9] = iou;
#pragma unroll
                for (int j = 9; j > 0; --j) {
                    float hi = fmaxf(V[j-1], V[j]), lo = fminf(V[j-1], V[j]);
                    V[j-1] = hi; V[j] = lo;
                }
            }
        }
    }

    int lane = tid & 63, wid = tid >> 6;
    __shared__ float wTop[4][10];
    float out[10];
#pragma unroll
    for (int r = 0; r < 10; ++r) {
        uint64_t pk = ((uint64_t)fkey(V[0]) << 32) | (uint32_t)lane;
        pk = wmax64(pk);
        int wl = (int)(pk & 63u);
        out[r] = __shfl(V[0], wl);
        bool win = (lane == wl);
#pragma unroll
        for (int j = 0; j < 9; ++j) V[j] = win ? V[j+1] : V[j];
        V[9] = win ? -1.0f : V[9];
    }
    if (lane == 0) {
#pragma unroll
        for (int r = 0; r < 10; ++r) wTop[wid][r] = out[r];
    }
    __syncthreads();
    if (wid == 0) {
        float x = (lane < 40) ? wTop[lane / 10][lane % 10] : -1.0f;
        int base_out = bt * (SL * 10) + sl * 10;
#pragma unroll
        for (int r = 0; r < 10; ++r) {
            uint64_t pk = ((uint64_t)fkey(x) << 32) | (uint32_t)lane;
            pk = wmax64(pk);
            int wl = (int)(pk & 63u);
            float v = __shfl(x, wl);
            if (lane == 0) candV[base_out + r] = v;
            if (lane == wl) x = -1.0f;
        }
    }
}

// ---------------- Phase Bc: cost top-10, dyn_k, mm bits + exactly-once matched compaction ----------------
__global__ __launch_bounds__(BDIM) void phaseBc(
    const float* __restrict__ preds, const float* __restrict__ tgt,
    const float4* __restrict__ box4, const float* __restrict__ sobjv,
    const float* __restrict__ Sbuf, const uint32_t* __restrict__ fgim,
    const int* __restrict__ cnt, const int* __restrict__ candIdx,
    const float* __restrict__ candV, uint32_t* __restrict__ mm,
    int* __restrict__ mcnt, int* __restrict__ mlist)
{
    int bt = blockIdx.x;
    int b = bt / Tn, t = bt % Tn;
    const float* tr = tgt + (size_t)bt * 6;
    if ((int)tr[0] != b) return;
    int ct = (int)tr[1];
    float tx1 = tr[2], ty1 = tr[3], tx2 = tr[4], ty2 = tr[5];
    float areaT = (tx2 - tx1) * (ty2 - ty1);
    int tid = threadIdx.x, lane = tid & 63, wid = tid >> 6;
    int baseg = b * An;
    int M = cnt[bt];
    bool slow = (M < 10) || (M > CAP);

    uint64_t L[10];
#pragma unroll
    for (int j = 0; j < 10; ++j) L[j] = ~0ULL;

    if (!slow) {
        for (int i = tid; i < M; i += BDIM) {
            int a = candIdx[bt * CAP + i];
            int g = baseg + a;
            float4 pb = box4[g];
            float areaP = (pb.z - pb.x) * (pb.w - pb.y);
            float w = fmaxf(fminf(tx2, pb.z) - fmaxf(tx1, pb.x), 0.0f);
            float h = fmaxf(fminf(ty2, pb.w) - fmaxf(ty1, pb.y), 0.0f);
            float inter = w * h;
            float iou = inter / (areaT + areaP - inter + 1e-8f);
            float z = preds[(size_t)g * 85 + 5 + ct];
            float pr = fsqrt(sobjv[g] * fsigm(z));
            pr = fminf(fmaxf(pr, 1e-7f), 1.0f - 1e-7f);
            float clsc = -(flogn(pr) + Sbuf[g] - flogn(1.0f - pr));
            float cost = clsc - 3.0f * flogn(iou + 1e-8f);  // matched => +0 penalties
            uint64_t k = ((uint64_t)fkey(cost) << 32) | (uint32_t)a;
            uint64_t m9 = (k < L[9]) ? k : L[9];
            L[9] = m9;
#pragma unroll
            for (int j = 9; j > 0; --j) {
                uint64_t lo = (L[j-1] < L[j]) ? L[j-1] : L[j];
                uint64_t hi = (L[j-1] < L[j]) ? L[j] : L[j-1];
                L[j-1] = lo; L[j] = hi;
            }
        }
    } else {
        for (int a = tid; a < An; a += BDIM) {
            int g = baseg + a;
            uint32_t fi = fgim[g];
            float4 pb = box4[g];
            float areaP = (pb.z - pb.x) * (pb.w - pb.y);
            float w = fmaxf(fminf(tx2, pb.z) - fmaxf(tx1, pb.x), 0.0f);
            float h = fmaxf(fminf(ty2, pb.w) - fmaxf(ty1, pb.y), 0.0f);
            float inter = w * h;
            float iou = inter / (areaT + areaP - inter + 1e-8f);
            float z = preds[(size_t)g * 85 + 5 + ct];
            float pr = fsqrt(sobjv[g] * fsigm(z));
            pr = fminf(fmaxf(pr, 1e-7f), 1.0f - 1e-7f);
            float clsc = -(flogn(pr) + Sbuf[g] - flogn(1.0f - pr));
            float cost = clsc - 3.0f * flogn(iou + 1e-8f)
                       + (((fi >> t) & 1u) ? 0.0f : 100000.0f)
                       + ((fi & 0x80000000u) ? 0.0f : 1000000.0f);
            uint64_t k = ((uint64_t)fkey(cost) << 32) | (uint32_t)a;
            uint64_t m9 = (k < L[9]) ? k : L[9];
            L[9] = m9;
#pragma unroll
            for (int j = 9; j > 0; --j) {
                uint64_t lo = (L[j-1] < L[j]) ? L[j-1] : L[j];
                uint64_t hi = (L[j-1] < L[j]) ? L[j] : L[j-1];
                L[j-1] = lo; L[j] = hi;
            }
        }
    }

    __shared__ uint64_t wT[4][10];
    __shared__ int s_sel[10];
    __shared__ int s_dynk;
    uint64_t wout[10];
#pragma unroll
    for (int r = 0; r < 10; ++r) {
        uint64_t m = wmin64(L[0]);
        wout[r] = m;
        bool win = (L[0] == m) && (m != ~0ULL);
#pragma unroll
        for (int j = 0; j < 9; ++j) L[j] = win ? L[j+1] : L[j];
        L[9] = win ? ~0ULL : L[9];
    }
    if (lane == 0) {
#pragma unroll
        for (int r = 0; r < 10; ++r) wT[wid][r] = wout[r];
    }
    __syncthreads();
    if (wid == 0) {
        // merge 40 wave-top keys -> global top-10 (ascending cost, lex)
        uint64_t x = (lane < 40) ? wT[lane / 10][lane % 10] : ~0ULL;
#pragma unroll
        for (int r = 0; r < 10; ++r) {
            uint64_t m = wmin64(x);
            if (lane == 0) s_sel[r] = (int)(m & 0xFFFFFFFFu);
            if (x == m && m != ~0ULL) x = ~0ULL;
        }
        // merge SL*10 slice iou tops -> dyn_k (descending accumulate)
        const float* cv = candV + bt * (SL * 10);
        float v0 = cv[lane];
        float v1 = (lane < SL * 10 - 64) ? cv[lane + 64] : -1.0f;
        float accum = 0.0f;
#pragma unroll
        for (int r = 0; r < 10; ++r) {
            bool p0 = (v0 >= v1);
            float hv = p0 ? v0 : v1;
            uint32_t slot = p0 ? (uint32_t)lane : (uint32_t)(lane + 64);
            uint64_t pk = ((uint64_t)fkey(hv) << 32) | slot;
            pk = wmax64(pk);
            int ws = (int)(pk & 127u);
            float v = __uint_as_float(unfkey((uint32_t)(pk >> 32)));
            accum += v;
            if (ws == lane) v0 = -1.0f;
            else if (ws == lane + 64) v1 = -1.0f;
        }
        if (lane == 0) {
            int dynk = (int)accum;            // trunc == astype(int32)
            s_dynk = min(max(dynk, 1), 10);
        }
    }
    __syncthreads();
    if (tid < s_dynk) {
        int a = s_sel[tid];
        int g = baseg + a;
        if (fgim[g] & 0x80000000u) {
            // exactly-once matched-anchor compaction: first claimant inserts g
            if (atomicOr((unsigned int*)&mm[g], 1u << t) == 0u) {
                int pos = atomicAdd(mcnt, 1);
                if (pos < MCAP) mlist[pos] = g;
            }
        }
    }
}

// ---------------- Phase D: heavy per-matched-anchor loss (compact, tgt in LDS) ----------------
__global__ __launch_bounds__(BDIM) void phaseD(
    const float* __restrict__ preds, const float* __restrict__ tgt,
    const float4* __restrict__ box4, const float* __restrict__ sobjv,
    const float* __restrict__ Sbuf, const uint32_t* __restrict__ fgim,
    const uint32_t* __restrict__ mm, const int* __restrict__ mcnt,
    const int* __restrict__ mlist,
    float* __restrict__ lboxA, float* __restrict__ lobjA)
{
    __shared__ float tT[Bn * Tn * 6];
    for (int i = threadIdx.x; i < Bn * Tn * 6; i += BDIM) tT[i] = tgt[i];
    __syncthreads();

    int n = min(*mcnt, MCAP);
    for (int i = blockIdx.x * BDIM + threadIdx.x; i < n; i += gridDim.x * BDIM) {
        int g = mlist[i];
        int b = g / An;
        float4 pb = box4[g];
        float px1 = pb.x, py1 = pb.y, px2 = pb.z, py2 = pb.w;
        uint32_t m = mm[g];
        int pc = __popc(m);

        int at; float pred_iou;
        if (pc == 1) {
            at = __ffs(m) - 1;
            const float* trr = tT + (b * Tn + at) * 6;
            float tx1 = trr[2], ty1 = trr[3], tx2 = trr[4], ty2 = trr[5];
            float areaT = (tx2 - tx1) * (ty2 - ty1);
            float areaP = (px2 - px1) * (py2 - py1);
            float w = fmaxf(fminf(tx2, px2) - fmaxf(tx1, px1), 0.0f);
            float h = fmaxf(fminf(ty2, py2) - fmaxf(ty1, py1), 0.0f);
            float inter = w * h;
            pred_iou = inter / (areaT + areaP - inter + 1e-8f);
        } else {
            float S = Sbuf[g];
            uint32_t fi = fgim[g];
            float sobj = sobjv[g];
            float areaP = (px2 - px1) * (py2 - py1);
            float best = INFINITY;
            at = -1; pred_iou = 0.0f;
            for (int t = 0; t < Tn; ++t) {
                const float* trr = tT + (b * Tn + t) * 6;
                bool valid = ((int)trr[0] == b);
                int ctt = (int)trr[1];
                float tx1 = trr[2], ty1 = trr[3], tx2 = trr[4], ty2 = trr[5];
                float areaT = (tx2 - tx1) * (ty2 - ty1);
                float w = fmaxf(fminf(tx2, px2) - fmaxf(tx1, px1), 0.0f);
                float h = fmaxf(fminf(ty2, py2) - fmaxf(ty1, py1), 0.0f);
                float inter = w * h;
                float iou = inter / (areaT + areaP - inter + 1e-8f);
                float z = preds[(size_t)g * 85 + 5 + ctt];
                float pr = fsqrt(sobj * fsigm(z));
                pr = fminf(fmaxf(pr, 1e-7f), 1.0f - 1e-7f);
                float clsc = valid ? -(flogn(pr) + S - flogn(1.0f - pr)) : -S;
                float cost = clsc - 3.0f * flogn(iou + 1e-8f)
                           + (((fi >> t) & 1u) ? 0.0f : 100000.0f)
                           + ((fi & 0x80000000u) ? 0.0f : 1000000.0f)
                           + (valid ? 0.0f : 1000000000.0f);
                if (cost < best) { best = cost; at = t; pred_iou = iou; }
            }
        }

        const float* trr = tT + (b * Tn + at) * 6;
        float bx1 = trr[2], by1 = trr[3], bx2 = trr[4], by2 = trr[5];
        float w = fmaxf(fminf(px2, bx2) - fmaxf(px1, bx1), 0.0f);
        float h = fmaxf(fminf(py2, by2) - fmaxf(py1, by1), 0.0f);
        float inter = w * h;
        float wa = px2 - px1, ha = py2 - py1, wb = bx2 - bx1, hb = by2 - by1;
        float uni = wa * ha + wb * hb - inter + 1e-7f;
        float iou = inter / uni;
        float cw = fmaxf(px2, bx2) - fminf(px1, bx1);
        float ch = fmaxf(py2, by2) - fminf(py1, by1);
        float c2 = cw * cw + ch * ch + 1e-7f;
        float dx = px1 + px2 - bx1 - bx2, dy = py1 + py2 - by1 - by2;
        float rho2 = (dx * dx + dy * dy) / 4.0f;
        float dat = atanf(wb / (hb + 1e-7f)) - atanf(wa / (ha + 1e-7f));
        float v = 0.4052847345693511f * dat * dat;     // 4/pi^2
        float alpha = v / (1.0f - iou + v + 1e-7f);
        float ciou = iou - rho2 / c2 - alpha * v;

        int cls = (int)trr[1];
        bool pos = (pred_iou > 0.0f);
        const float* zp = preds + (size_t)g * 85 + 5;
        float lo = 0.0f;
        for (int c0 = 0; c0 < Cn; c0 += 8) {
            float z[8];
#pragma unroll
            for (int j = 0; j < 8; ++j) z[j] = zp[c0 + j];
#pragma unroll
            for (int j = 0; j < 8; ++j) {
                float y = (pos && (c0 + j) == cls) ? 0.95f : 6.329113924050633e-4f;
                lo += bce(z[j], y);
            }
        }
        lboxA[g] = 1.0f - ciou;
        lobjA[g] = lo;
    }
}

// ---------------- Phase EF: streaming assembly + fused reduce + last-block final ----------------
__global__ __launch_bounds__(BDIM) void phaseEF(
    const float* __restrict__ objzv, const uint32_t* __restrict__ mm,
    const float* __restrict__ lboxA, const float* __restrict__ lobjA,
    float* __restrict__ pLbox, float* __restrict__ pLobj,
    float* __restrict__ pLcls, float* __restrict__ pNpos,
    int* __restrict__ done, float* __restrict__ out)
{
    int tid = threadIdx.x;
    int g = blockIdx.x * BDIM + tid;
    uint32_t m = mm[g];
    bool matched = (m != 0u);
    float lbox_i = matched ? lboxA[g] : 0.0f;   // predicated: only written slots read
    float lobj_i = matched ? lobjA[g] : 0.0f;
    float npos_i = matched ? 1.0f : 0.0f;
    float lcls_i = bce(objzv[g], matched ? 1.0f : 0.0f);

    __shared__ float red4[4][BDIM];
    red4[0][tid] = lbox_i; red4[1][tid] = lobj_i;
    red4[2][tid] = lcls_i; red4[3][tid] = npos_i;
    __syncthreads();
    for (int s = BDIM / 2; s > 0; s >>= 1) {
        if (tid < s) {
            red4[0][tid] += red4[0][tid + s];
            red4[1][tid] += red4[1][tid + s];
            red4[2][tid] += red4[2][tid + s];
            red4[3][tid] += red4[3][tid + s];
        }
        __syncthreads();
    }
    __shared__ int s_last;
    if (tid == 0) {
        pLbox[blockIdx.x] = red4[0][0];
        pLobj[blockIdx.x] = red4[1][0];
        pLcls[blockIdx.x] = red4[2][0];
        pNpos[blockIdx.x] = red4[3][0];
        __threadfence();                          // release partials (device scope)
        int old = atomicAdd(done, 1);
        s_last = (old == NBLK_C - 1) ? 1 : 0;
    }
    __syncthreads();
    if (!s_last) return;
    __threadfence();                              // acquire all partials

    // finalK body verbatim (same order -> bit-identical)
    float s0 = 0, s1 = 0, s2 = 0, s3 = 0;
    for (int i = tid; i < NBLK_C; i += BDIM) {
        s0 += pLbox[i]; s1 += pLobj[i]; s2 += pLcls[i]; s3 += pNpos[i];
    }
    red4[0][tid] = s0; red4[1][tid] = s1; red4[2][tid] = s2; red4[3][tid] = s3;
    __syncthreads();
    for (int s = BDIM / 2; s > 0; s >>= 1) {
        if (tid < s) {
            red4[0][tid] += red4[0][tid + s];
            red4[1][tid] += red4[1][tid + s];
            red4[2][tid] += red4[2][tid + s];
            red4[3][tid] += red4[3][tid + s];
        }
        __syncthreads();
    }
    if (tid == 0) {
        float npos = fmaxf(red4[3][0], 1.0f);
        float lbox = red4[0][0] / npos;
        float lobj = red4[1][0] / (npos * (float)Cn);
        float lcls = red4[2][0] / (float)(Bn * An);
        out[0] = lbox + lobj + lcls;
        out[1] = lbox;
        out[2] = lobj;
        out[3] = lcls;
    }
}

extern "C" void kernel_launch(void* const* d_in, const int* in_sizes, int n_in,
                              void* d_out, int out_size, void* d_ws, size_t ws_size,
                              hipStream_t stream)
{
    (void)in_sizes; (void)n_in; (void)out_size; (void)ws_size;
    const float* preds = (const float*)d_in[0];
    const float* grid  = (const float*)d_in[1];
    const float* strd  = (const float*)d_in[2];
    const float* tgt   = (const float*)d_in[3];

    char* ws = (char*)d_ws;
    float4*   box4  = (float4*)ws;   ws += (size_t)BA * 16;
    float*    sobjv = (float*)ws;    ws += (size_t)BA * 4;
    float*    objzv = (float*)ws;    ws += (size_t)BA * 4;
    float*    Sbuf  = (float*)ws;    ws += (size_t)BA * 4;
    uint32_t* fgim  = (uint32_t*)ws; ws += (size_t)BA * 4;
    uint32_t* mm    = (uint32_t*)ws; ws += (size_t)BA * 4;
    int*      cnt   = (int*)ws;      ws += (size_t)Bn * Tn * 4;
    int*      mcnt  = (int*)ws;      ws += 16;
    int*      done  = (int*)ws;      ws += 16;
    int*   mlist   = (int*)ws;       ws += (size_t)MCAP * 4;
    float* lboxA   = (float*)ws;     ws += (size_t)BA * 4;
    float* lobjA   = (float*)ws;     ws += (size_t)BA * 4;
    int*   candIdx = (int*)ws;       ws += (size_t)Bn * Tn * CAP * 4;
    float* candV   = (float*)ws;     ws += (size_t)Bn * Tn * SL * 10 * 4;
    float* pLbox = (float*)ws;       ws += (size_t)NBLK_C * 4;
    float* pLobj = (float*)ws;       ws += (size_t)NBLK_C * 4;
    float* pLcls = (float*)ws;       ws += (size_t)NBLK_C * 4;
    float* pNpos = (float*)ws;       ws += (size_t)NBLK_C * 4;

    phaseA<<<Bn * BLK_PER_IMG, BDIM, 0, stream>>>(preds, grid, strd, tgt,
                                                  box4, sobjv, objzv, Sbuf, fgim,
                                                  mm, cnt, mcnt, done);
    phaseBs<<<Bn * Tn * SL, BDIM, 0, stream>>>(tgt, box4, fgim, cnt, candIdx, candV);
    phaseBc<<<Bn * Tn, BDIM, 0, stream>>>(preds, tgt, box4, sobjv, Sbuf, fgim,
                                          cnt, candIdx, candV, mm, mcnt, mlist);
    phaseD<<<32, BDIM, 0, stream>>>(preds, tgt, box4, sobjv, Sbuf, fgim, mm,
                                    mcnt, mlist, lboxA, lobjA);
    phaseEF<<<NBLK_C, BDIM, 0, stream>>>(objzv, mm, lboxA, lobjA,
                                         pLbox, pLobj, pLcls, pNpos,
                                         done, (float*)d_out);
}

// Round 13
// 130.426 us; speedup vs baseline: 1.6759x; 1.3463x over previous
//
#include <hip/hip_runtime.h>
#include <cstdint>
#include <cstddef>

#define BDIM 256
constexpr int Bn = 16;
constexpr int Tn = 20;
constexpr int Cn = 80;
constexpr int An = 33600;                 // 160^2 + 80^2 + 40^2
constexpr int BA = Bn * An;
constexpr int NBLK_C = BA / BDIM;         // 2100 exact
constexpr int SL = 8;                     // slices per (b,t) in phaseBs
constexpr int ANB = An / SL;              // 4200 exact
constexpr int CAP = 2048;                 // matched-candidate list capacity
constexpr int MCAP = 4096;                // matched-anchor list capacity (true max 3200)
constexpr int BLK_PER_IMG = An * 8 / BDIM; // 1050 exact (phaseA blocks never straddle images)

__device__ __forceinline__ float bce(float z, float y) {
    return fmaxf(z, 0.0f) - z * y + log1pf(expf(-fabsf(z)));
}

// ---- fast HW transcendentals (~1 ulp) — used ONLY in the discrete selection path ----
constexpr float LOG2E = 1.4426950408889634f;
constexpr float LN2   = 0.6931471805599453f;
__device__ __forceinline__ float fexp2(float x){ float r; asm("v_exp_f32 %0, %1" : "=v"(r) : "v"(x)); return r; }
__device__ __forceinline__ float flog2(float x){ float r; asm("v_log_f32 %0, %1" : "=v"(r) : "v"(x)); return r; }
__device__ __forceinline__ float frcp (float x){ float r; asm("v_rcp_f32 %0, %1" : "=v"(r) : "v"(x)); return r; }
__device__ __forceinline__ float fsqrt(float x){ float r; asm("v_sqrt_f32 %0, %1" : "=v"(r) : "v"(x)); return r; }
__device__ __forceinline__ float fsigm(float z){ return frcp(1.0f + fexp2(-z * LOG2E)); }
__device__ __forceinline__ float flogn(float x){ return flog2(x) * LN2; }

// monotone float->uint mapping (ascending uint == ascending float, handles negatives)
__device__ __forceinline__ uint32_t fkey(float f) {
    uint32_t b = __float_as_uint(f);
    return (b & 0x80000000u) ? ~b : (b | 0x80000000u);
}
__device__ __forceinline__ uint32_t unfkey(uint32_t u) {
    return (u & 0x80000000u) ? (u & 0x7FFFFFFFu) : ~u;
}
__device__ __forceinline__ uint64_t wmin64(uint64_t x) {
#pragma unroll
    for (int off = 1; off < 64; off <<= 1) {
        uint64_t o = (uint64_t)__shfl_xor((unsigned long long)x, off);
        x = (o < x) ? o : x;
    }
    return x;
}
__device__ __forceinline__ uint64_t wmax64(uint64_t x) {
#pragma unroll
    for (int off = 1; off < 64; off <<= 1) {
        uint64_t o = (uint64_t)__shfl_xor((unsigned long long)x, off);
        x = (o > x) ? o : x;
    }
    return x;
}

// ---------------- Phase A: 8 threads/anchor, fast trans; zeros mm/cnt/mcnt; tgt in LDS ----------------
__global__ __launch_bounds__(BDIM) void phaseA(
    const float* __restrict__ preds, const float* __restrict__ grid,
    const float* __restrict__ strd, const float* __restrict__ tgt,
    float4* __restrict__ box4, float* __restrict__ sobjv, float* __restrict__ objzv,
    float* __restrict__ Sbuf, uint32_t* __restrict__ fgim,
    uint32_t* __restrict__ mm, int* __restrict__ cnt, int* __restrict__ mcnt)
{
    __shared__ float tT[Tn * 6];
    int tid = threadIdx.x;
    int b = blockIdx.x / BLK_PER_IMG;             // blocks never straddle images
    if (tid < Tn * 6) tT[tid] = tgt[b * Tn * 6 + tid];
    if (blockIdx.x == 0) {                        // zero selection counters (runs pre-phaseBs)
        for (int i = tid; i < Bn * Tn; i += BDIM) cnt[i] = 0;
        if (tid == 0) *mcnt = 0;
    }
    __syncthreads();

    int idx = blockIdx.x * BDIM + tid;            // over BA*8 threads
    int g = idx >> 3, q = idx & 7;
    int a = g - b * An;
    const float* r = preds + (size_t)g * 85;

    float objz = r[4];
    float sobj = fsigm(objz);
    float S2 = 0.0f;                              // sum of log2(1-pr)
#pragma unroll
    for (int cc = 0; cc < 10; ++cc) {
        int c = q + 8 * cc;
        float z = r[5 + c];
        float pr = fsqrt(sobj * fsigm(z));
        pr = fminf(fmaxf(pr, 1e-7f), 1.0f - 1e-7f);
        S2 += flog2(1.0f - pr);
    }
    S2 += __shfl_xor(S2, 1);
    S2 += __shfl_xor(S2, 2);
    S2 += __shfl_xor(S2, 4);

    float gx = grid[a * 2], gy = grid[a * 2 + 1], sv = strd[a];
    float xc = (gx + 0.5f) * sv, yc = (gy + 0.5f) * sv;
    uint32_t im_p = 0, fg_p = 0;
#pragma unroll
    for (int k = 0; k < 3; ++k) {
        int t = q + 8 * k;
        if (t < Tn) {
            const float* trr = tT + t * 6;
            bool valid = ((int)trr[0] == b);
            float x1 = trr[2], y1 = trr[3], x2 = trr[4], y2 = trr[5];
            float dmin = fminf(fminf(xc - x1, yc - y1), fminf(x2 - xc, y2 - yc));
            bool inb = (dmin > 0.0f) && valid;
            float cxt = (x1 + x2) * 0.5f, cyt = (y1 + y2) * 0.5f;
            bool inc = (fmaxf(fabsf(xc - cxt), fabsf(yc - cyt)) < 2.5f * sv) && valid;
            if (inb || inc) fg_p = 1u;
            if (inb && inc) im_p |= (1u << t);
        }
    }
    im_p |= __shfl_xor(im_p, 1); im_p |= __shfl_xor(im_p, 2); im_p |= __shfl_xor(im_p, 4);
    fg_p |= __shfl_xor(fg_p, 1); fg_p |= __shfl_xor(fg_p, 2); fg_p |= __shfl_xor(fg_p, 4);

    if (q == 0) {
        box4[g] = make_float4(r[0], r[1], r[2], r[3]);
        sobjv[g] = sobj; objzv[g] = objz; Sbuf[g] = S2 * LN2;
        fgim[g] = im_p | (fg_p ? 0x80000000u : 0u);
        mm[g] = 0u;                               // replaces hipMemsetAsync
    }
}

// ---------------- Phase Bs: slice-parallel cheap scan (2560 blocks) ----------------
__global__ __launch_bounds__(BDIM) void phaseBs(
    const float* __restrict__ tgt, const float4* __restrict__ box4,
    const uint32_t* __restrict__ fgim,
    int* __restrict__ cnt, int* __restrict__ candIdx, float* __restrict__ candV)
{
    int bt = blockIdx.x / SL, sl = blockIdx.x % SL;
    int b = bt / Tn, t = bt % Tn;
    const float* tr = tgt + (size_t)bt * 6;
    if ((int)tr[0] != b) return;
    float tx1 = tr[2], ty1 = tr[3], tx2 = tr[4], ty2 = tr[5];
    float areaT = (tx2 - tx1) * (ty2 - ty1);
    int tid = threadIdx.x;
    int baseg = b * An;
    uint32_t tmask = 1u << t;

    float V[10];                          // sorted desc, branch-free inserts
#pragma unroll
    for (int j = 0; j < 10; ++j) V[j] = 0.0f;

    int aend = (sl + 1) * ANB;
    for (int a = sl * ANB + tid; a < aend; a += BDIM) {
        int g = baseg + a;
        uint32_t fi = fgim[g];
        if (fi & tmask) {
            int pos = atomicAdd(&cnt[bt], 1);
            if (pos < CAP) candIdx[bt * CAP + pos] = a;
        }
        if (fi & 0x80000000u) {
            float4 pb = box4[g];
            float areaP = (pb.z - pb.x) * (pb.w - pb.y);
            float w = fmaxf(fminf(tx2, pb.z) - fmaxf(tx1, pb.x), 0.0f);
            float h = fmaxf(fminf(ty2, pb.w) - fmaxf(ty1, pb.y), 0.0f);
            float inter = w * h;
            float iou = inter / (areaT + areaP - inter + 1e-8f);
            if (iou > V[9]) {
                V[9] = iou;
#pragma unroll
                for (int j = 9; j > 0; --j) {
                    float hi = fmaxf(V[j-1], V[j]), lo = fminf(V[j-1], V[j]);
                    V[j-1] = hi; V[j] = lo;
                }
            }
        }
    }

    int lane = tid & 63, wid = tid >> 6;
    __shared__ float wTop[4][10];
    float out[10];
#pragma unroll
    for (int r = 0; r < 10; ++r) {
        uint64_t pk = ((uint64_t)fkey(V[0]) << 32) | (uint32_t)lane;
        pk = wmax64(pk);
        int wl = (int)(pk & 63u);
        out[r] = __shfl(V[0], wl);
        bool win = (lane == wl);
#pragma unroll
        for (int j = 0; j < 9; ++j) V[j] = win ? V[j+1] : V[j];
        V[9] = win ? -1.0f : V[9];
    }
    if (lane == 0) {
#pragma unroll
        for (int r = 0; r < 10; ++r) wTop[wid][r] = out[r];
    }
    __syncthreads();
    if (wid == 0) {
        float x = (lane < 40) ? wTop[lane / 10][lane % 10] : -1.0f;
        int base_out = bt * (SL * 10) + sl * 10;
#pragma unroll
        for (int r = 0; r < 10; ++r) {
            uint64_t pk = ((uint64_t)fkey(x) << 32) | (uint32_t)lane;
            pk = wmax64(pk);
            int wl = (int)(pk & 63u);
            float v = __shfl(x, wl);
            if (lane == 0) candV[base_out + r] = v;
            if (lane == wl) x = -1.0f;
        }
    }
}

// ---------------- Phase Bc: cost top-10, dyn_k, mm bits + exactly-once matched compaction ----------------
__global__ __launch_bounds__(BDIM) void phaseBc(
    const float* __restrict__ preds, const float* __restrict__ tgt,
    const float4* __restrict__ box4, const float* __restrict__ sobjv,
    const float* __restrict__ Sbuf, const uint32_t* __restrict__ fgim,
    const int* __restrict__ cnt, const int* __restrict__ candIdx,
    const float* __restrict__ candV, uint32_t* __restrict__ mm,
    int* __restrict__ mcnt, int* __restrict__ mlist)
{
    int bt = blockIdx.x;
    int b = bt / Tn, t = bt % Tn;
    const float* tr = tgt + (size_t)bt * 6;
    if ((int)tr[0] != b) return;
    int ct = (int)tr[1];
    float tx1 = tr[2], ty1 = tr[3], tx2 = tr[4], ty2 = tr[5];
    float areaT = (tx2 - tx1) * (ty2 - ty1);
    int tid = threadIdx.x, lane = tid & 63, wid = tid >> 6;
    int baseg = b * An;
    int M = cnt[bt];
    bool slow = (M < 10) || (M > CAP);

    uint64_t L[10];
#pragma unroll
    for (int j = 0; j < 10; ++j) L[j] = ~0ULL;

    if (!slow) {
        for (int i = tid; i < M; i += BDIM) {
            int a = candIdx[bt * CAP + i];
            int g = baseg + a;
            float4 pb = box4[g];
            float areaP = (pb.z - pb.x) * (pb.w - pb.y);
            float w = fmaxf(fminf(tx2, pb.z) - fmaxf(tx1, pb.x), 0.0f);
            float h = fmaxf(fminf(ty2, pb.w) - fmaxf(ty1, pb.y), 0.0f);
            float inter = w * h;
            float iou = inter / (areaT + areaP - inter + 1e-8f);
            float z = preds[(size_t)g * 85 + 5 + ct];
            float pr = fsqrt(sobjv[g] * fsigm(z));
            pr = fminf(fmaxf(pr, 1e-7f), 1.0f - 1e-7f);
            float clsc = -(flogn(pr) + Sbuf[g] - flogn(1.0f - pr));
            float cost = clsc - 3.0f * flogn(iou + 1e-8f);  // matched => +0 penalties
            uint64_t k = ((uint64_t)fkey(cost) << 32) | (uint32_t)a;
            uint64_t m9 = (k < L[9]) ? k : L[9];
            L[9] = m9;
#pragma unroll
            for (int j = 9; j > 0; --j) {
                uint64_t lo = (L[j-1] < L[j]) ? L[j-1] : L[j];
                uint64_t hi = (L[j-1] < L[j]) ? L[j] : L[j-1];
                L[j-1] = lo; L[j] = hi;
            }
        }
    } else {
        for (int a = tid; a < An; a += BDIM) {
            int g = baseg + a;
            uint32_t fi = fgim[g];
            float4 pb = box4[g];
            float areaP = (pb.z - pb.x) * (pb.w - pb.y);
            float w = fmaxf(fminf(tx2, pb.z) - fmaxf(tx1, pb.x), 0.0f);
            float h = fmaxf(fminf(ty2, pb.w) - fmaxf(ty1, pb.y), 0.0f);
            float inter = w * h;
            float iou = inter / (areaT + areaP - inter + 1e-8f);
            float z = preds[(size_t)g * 85 + 5 + ct];
            float pr = fsqrt(sobjv[g] * fsigm(z));
            pr = fminf(fmaxf(pr, 1e-7f), 1.0f - 1e-7f);
            float clsc = -(flogn(pr) + Sbuf[g] - flogn(1.0f - pr));
            float cost = clsc - 3.0f * flogn(iou + 1e-8f)
                       + (((fi >> t) & 1u) ? 0.0f : 100000.0f)
                       + ((fi & 0x80000000u) ? 0.0f : 1000000.0f);
            uint64_t k = ((uint64_t)fkey(cost) << 32) | (uint32_t)a;
            uint64_t m9 = (k < L[9]) ? k : L[9];
            L[9] = m9;
#pragma unroll
            for (int j = 9; j > 0; --j) {
                uint64_t lo = (L[j-1] < L[j]) ? L[j-1] : L[j];
                uint64_t hi = (L[j-1] < L[j]) ? L[j] : L[j-1];
                L[j-1] = lo; L[j] = hi;
            }
        }
    }

    __shared__ uint64_t wT[4][10];
    __shared__ int s_sel[10];
    __shared__ int s_dynk;
    uint64_t wout[10];
#pragma unroll
    for (int r = 0; r < 10; ++r) {
        uint64_t m = wmin64(L[0]);
        wout[r] = m;
        bool win = (L[0] == m) && (m != ~0ULL);
#pragma unroll
        for (int j = 0; j < 9; ++j) L[j] = win ? L[j+1] : L[j];
        L[9] = win ? ~0ULL : L[9];
    }
    if (lane == 0) {
#pragma unroll
        for (int r = 0; r < 10; ++r) wT[wid][r] = wout[r];
    }
    __syncthreads();
    if (wid == 0) {
        // merge 40 wave-top keys -> global top-10 (ascending cost, lex)
        uint64_t x = (lane < 40) ? wT[lane / 10][lane % 10] : ~0ULL;
#pragma unroll
        for (int r = 0; r < 10; ++r) {
            uint64_t m = wmin64(x);
            if (lane == 0) s_sel[r] = (int)(m & 0xFFFFFFFFu);
            if (x == m && m != ~0ULL) x = ~0ULL;
        }
        // merge SL*10 slice iou tops -> dyn_k (descending accumulate)
        const float* cv = candV + bt * (SL * 10);
        float v0 = cv[lane];
        float v1 = (lane < SL * 10 - 64) ? cv[lane + 64] : -1.0f;
        float accum = 0.0f;
#pragma unroll
        for (int r = 0; r < 10; ++r) {
            bool p0 = (v0 >= v1);
            float hv = p0 ? v0 : v1;
            uint32_t slot = p0 ? (uint32_t)lane : (uint32_t)(lane + 64);
            uint64_t pk = ((uint64_t)fkey(hv) << 32) | slot;
            pk = wmax64(pk);
            int ws = (int)(pk & 127u);
            float v = __uint_as_float(unfkey((uint32_t)(pk >> 32)));
            accum += v;
            if (ws == lane) v0 = -1.0f;
            else if (ws == lane + 64) v1 = -1.0f;
        }
        if (lane == 0) {
            int dynk = (int)accum;            // trunc == astype(int32)
            s_dynk = min(max(dynk, 1), 10);
        }
    }
    __syncthreads();
    if (tid < s_dynk) {
        int a = s_sel[tid];
        int g = baseg + a;
        if (fgim[g] & 0x80000000u) {
            // exactly-once matched-anchor compaction: first claimant inserts g
            if (atomicOr((unsigned int*)&mm[g], 1u << t) == 0u) {
                int pos = atomicAdd(mcnt, 1);
                if (pos < MCAP) mlist[pos] = g;
            }
        }
    }
}

// ---------------- Phase D: heavy per-matched-anchor loss (compact, tgt in LDS) ----------------
__global__ __launch_bounds__(BDIM) void phaseD(
    const float* __restrict__ preds, const float* __restrict__ tgt,
    const float4* __restrict__ box4, const float* __restrict__ sobjv,
    const float* __restrict__ Sbuf, const uint32_t* __restrict__ fgim,
    const uint32_t* __restrict__ mm, const int* __restrict__ mcnt,
    const int* __restrict__ mlist,
    float* __restrict__ lboxA, float* __restrict__ lobjA)
{
    __shared__ float tT[Bn * Tn * 6];
    for (int i = threadIdx.x; i < Bn * Tn * 6; i += BDIM) tT[i] = tgt[i];
    __syncthreads();

    int n = min(*mcnt, MCAP);
    for (int i = blockIdx.x * BDIM + threadIdx.x; i < n; i += gridDim.x * BDIM) {
        int g = mlist[i];
        int b = g / An;
        float4 pb = box4[g];
        float px1 = pb.x, py1 = pb.y, px2 = pb.z, py2 = pb.w;
        uint32_t m = mm[g];
        int pc = __popc(m);

        int at; float pred_iou;
        if (pc == 1) {
            at = __ffs(m) - 1;
            const float* trr = tT + (b * Tn + at) * 6;
            float tx1 = trr[2], ty1 = trr[3], tx2 = trr[4], ty2 = trr[5];
            float areaT = (tx2 - tx1) * (ty2 - ty1);
            float areaP = (px2 - px1) * (py2 - py1);
            float w = fmaxf(fminf(tx2, px2) - fmaxf(tx1, px1), 0.0f);
            float h = fmaxf(fminf(ty2, py2) - fmaxf(ty1, py1), 0.0f);
            float inter = w * h;
            pred_iou = inter / (areaT + areaP - inter + 1e-8f);
        } else {
            float S = Sbuf[g];
            uint32_t fi = fgim[g];
            float sobj = sobjv[g];
            float areaP = (px2 - px1) * (py2 - py1);
            float best = INFINITY;
            at = -1; pred_iou = 0.0f;
            for (int t = 0; t < Tn; ++t) {
                const float* trr = tT + (b * Tn + t) * 6;
                bool valid = ((int)trr[0] == b);
                int ctt = (int)trr[1];
                float tx1 = trr[2], ty1 = trr[3], tx2 = trr[4], ty2 = trr[5];
                float areaT = (tx2 - tx1) * (ty2 - ty1);
                float w = fmaxf(fminf(tx2, px2) - fmaxf(tx1, px1), 0.0f);
                float h = fmaxf(fminf(ty2, py2) - fmaxf(ty1, py1), 0.0f);
                float inter = w * h;
                float iou = inter / (areaT + areaP - inter + 1e-8f);
                float z = preds[(size_t)g * 85 + 5 + ctt];
                float pr = fsqrt(sobj * fsigm(z));
                pr = fminf(fmaxf(pr, 1e-7f), 1.0f - 1e-7f);
                float clsc = valid ? -(flogn(pr) + S - flogn(1.0f - pr)) : -S;
                float cost = clsc - 3.0f * flogn(iou + 1e-8f)
                           + (((fi >> t) & 1u) ? 0.0f : 100000.0f)
                           + ((fi & 0x80000000u) ? 0.0f : 1000000.0f)
                           + (valid ? 0.0f : 1000000000.0f);
                if (cost < best) { best = cost; at = t; pred_iou = iou; }
            }
        }

        const float* trr = tT + (b * Tn + at) * 6;
        float bx1 = trr[2], by1 = trr[3], bx2 = trr[4], by2 = trr[5];
        float w = fmaxf(fminf(px2, bx2) - fmaxf(px1, bx1), 0.0f);
        float h = fmaxf(fminf(py2, by2) - fmaxf(py1, by1), 0.0f);
        float inter = w * h;
        float wa = px2 - px1, ha = py2 - py1, wb = bx2 - bx1, hb = by2 - by1;
        float uni = wa * ha + wb * hb - inter + 1e-7f;
        float iou = inter / uni;
        float cw = fmaxf(px2, bx2) - fminf(px1, bx1);
        float ch = fmaxf(py2, by2) - fminf(py1, by1);
        float c2 = cw * cw + ch * ch + 1e-7f;
        float dx = px1 + px2 - bx1 - bx2, dy = py1 + py2 - by1 - by2;
        float rho2 = (dx * dx + dy * dy) / 4.0f;
        float dat = atanf(wb / (hb + 1e-7f)) - atanf(wa / (ha + 1e-7f));
        float v = 0.4052847345693511f * dat * dat;     // 4/pi^2
        float alpha = v / (1.0f - iou + v + 1e-7f);
        float ciou = iou - rho2 / c2 - alpha * v;

        int cls = (int)trr[1];
        bool pos = (pred_iou > 0.0f);
        const float* zp = preds + (size_t)g * 85 + 5;
        float lo = 0.0f;
        for (int c0 = 0; c0 < Cn; c0 += 8) {
            float z[8];
#pragma unroll
            for (int j = 0; j < 8; ++j) z[j] = zp[c0 + j];
#pragma unroll
            for (int j = 0; j < 8; ++j) {
                float y = (pos && (c0 + j) == cls) ? 0.95f : 6.329113924050633e-4f;
                lo += bce(z[j], y);
            }
        }
        lboxA[g] = 1.0f - ciou;
        lobjA[g] = lo;
    }
}

// ---------------- Phase E: streaming per-anchor loss assembly + fused reduce ----------------
__global__ __launch_bounds__(BDIM) void phaseE(
    const float* __restrict__ objzv, const uint32_t* __restrict__ mm,
    const float* __restrict__ lboxA, const float* __restrict__ lobjA,
    float* __restrict__ pLbox, float* __restrict__ pLobj,
    float* __restrict__ pLcls, float* __restrict__ pNpos)
{
    int tid = threadIdx.x;
    int g = blockIdx.x * BDIM + tid;
    uint32_t m = mm[g];
    bool matched = (m != 0u);
    float lbox_i = matched ? lboxA[g] : 0.0f;   // predicated: only written slots read
    float lobj_i = matched ? lobjA[g] : 0.0f;
    float npos_i = matched ? 1.0f : 0.0f;
    float lcls_i = bce(objzv[g], matched ? 1.0f : 0.0f);

    // fused reduction: same pairing & s-order per component -> bit-identical partials
    __shared__ float red4[4][BDIM];
    red4[0][tid] = lbox_i; red4[1][tid] = lobj_i;
    red4[2][tid] = lcls_i; red4[3][tid] = npos_i;
    __syncthreads();
    for (int s = BDIM / 2; s > 0; s >>= 1) {
        if (tid < s) {
            red4[0][tid] += red4[0][tid + s];
            red4[1][tid] += red4[1][tid + s];
            red4[2][tid] += red4[2][tid + s];
            red4[3][tid] += red4[3][tid + s];
        }
        __syncthreads();
    }
    if (tid == 0) {
        pLbox[blockIdx.x] = red4[0][0];
        pLobj[blockIdx.x] = red4[1][0];
        pLcls[blockIdx.x] = red4[2][0];
        pNpos[blockIdx.x] = red4[3][0];
    }
}

// ---------------- Final: fused order-preserving reduce of 2100 partials ----------------
__global__ __launch_bounds__(BDIM) void finalK(
    const float* __restrict__ pLbox, const float* __restrict__ pLobj,
    const float* __restrict__ pLcls, const float* __restrict__ pNpos,
    float* __restrict__ out)
{
    int tid = threadIdx.x;
    float s0 = 0, s1 = 0, s2 = 0, s3 = 0;
    for (int i = tid; i < NBLK_C; i += BDIM) {
        s0 += pLbox[i]; s1 += pLobj[i]; s2 += pLcls[i]; s3 += pNpos[i];
    }
    __shared__ float red4[4][BDIM];
    red4[0][tid] = s0; red4[1][tid] = s1; red4[2][tid] = s2; red4[3][tid] = s3;
    __syncthreads();
    for (int s = BDIM / 2; s > 0; s >>= 1) {
        if (tid < s) {
            red4[0][tid] += red4[0][tid + s];
            red4[1][tid] += red4[1][tid + s];
            red4[2][tid] += red4[2][tid + s];
            red4[3][tid] += red4[3][tid + s];
        }
        __syncthreads();
    }
    if (tid == 0) {
        float npos = fmaxf(red4[3][0], 1.0f);
        float lbox = red4[0][0] / npos;
        float lobj = red4[1][0] / (npos * (float)Cn);
        float lcls = red4[2][0] / (float)(Bn * An);
        out[0] = lbox + lobj + lcls;
        out[1] = lbox;
        out[2] = lobj;
        out[3] = lcls;
    }
}

extern "C" void kernel_launch(void* const* d_in, const int* in_sizes, int n_in,
                              void* d_out, int out_size, void* d_ws, size_t ws_size,
                              hipStream_t stream)
{
    (void)in_sizes; (void)n_in; (void)out_size; (void)ws_size;
    const float* preds = (const float*)d_in[0];
    const float* grid  = (const float*)d_in[1];
    const float* strd  = (const float*)d_in[2];
    const float* tgt   = (const float*)d_in[3];

    char* ws = (char*)d_ws;
    float4*   box4  = (float4*)ws;   ws += (size_t)BA * 16;
    float*    sobjv = (float*)ws;    ws += (size_t)BA * 4;
    float*    objzv = (float*)ws;    ws += (size_t)BA * 4;
    float*    Sbuf  = (float*)ws;    ws += (size_t)BA * 4;
    uint32_t* fgim  = (uint32_t*)ws; ws += (size_t)BA * 4;
    uint32_t* mm    = (uint32_t*)ws; ws += (size_t)BA * 4;
    int*      cnt   = (int*)ws;      ws += (size_t)Bn * Tn * 4;
    int*      mcnt  = (int*)ws;      ws += 16;
    int*   mlist   = (int*)ws;       ws += (size_t)MCAP * 4;
    float* lboxA   = (float*)ws;     ws += (size_t)BA * 4;
    float* lobjA   = (float*)ws;     ws += (size_t)BA * 4;
    int*   candIdx = (int*)ws;       ws += (size_t)Bn * Tn * CAP * 4;
    float* candV   = (float*)ws;     ws += (size_t)Bn * Tn * SL * 10 * 4;
    float* pLbox = (float*)ws;       ws += (size_t)NBLK_C * 4;
    float* pLobj = (float*)ws;       ws += (size_t)NBLK_C * 4;
    float* pLcls = (float*)ws;       ws += (size_t)NBLK_C * 4;
    float* pNpos = (float*)ws;       ws += (size_t)NBLK_C * 4;

    phaseA<<<Bn * BLK_PER_IMG, BDIM, 0, stream>>>(preds, grid, strd, tgt,
                                                  box4, sobjv, objzv, Sbuf, fgim,
                                                  mm, cnt, mcnt);
    phaseBs<<<Bn * Tn * SL, BDIM, 0, stream>>>(tgt, box4, fgim, cnt, candIdx, candV);
    phaseBc<<<Bn * Tn, BDIM, 0, stream>>>(preds, tgt, box4, sobjv, Sbuf, fgim,
                                          cnt, candIdx, candV, mm, mcnt, mlist);
    phaseD<<<32, BDIM, 0, stream>>>(preds, tgt, box4, sobjv, Sbuf, fgim, mm,
                                    mcnt, mlist, lboxA, lobjA);
    phaseE<<<NBLK_C, BDIM, 0, stream>>>(objzv, mm, lboxA, lobjA,
                                        pLbox, pLobj, pLcls, pNpos);
    finalK<<<1, BDIM, 0, stream>>>(pLbox, pLobj, pLcls, pNpos, (float*)d_out);
}